// Round 22
// baseline (506.536 us; speedup 1.0000x reference)
//
#include <hip/hip_runtime.h>
#include <hip/hip_fp16.h>

#define T_DIM 2048
#define B_DIM 64
#define I_DIM 128
#define H_DIM 256
#define L_DIM 6
#define C_DIM 100
#define M_DIM (T_DIM * B_DIM)   // 131072 rows
#define S_DIM (B_DIM * H_DIM)   // 16384 chains
#define XCB 32                  // chains per scan block (64B row granule)
#define XSTR 145                // u32 stride per chain in LDS (16 chunks * 9 + pad)
#define XTT 256                 // timesteps per tile
#define XNT (T_DIM / XTT)       // 8 tiles
#define NGB 2048                // gemm blocks (psum minor dim)

typedef unsigned short u16;
typedef unsigned int   u32;
typedef _Float16 f16;
typedef f16   f16x8 __attribute__((ext_vector_type(8)));
typedef float f32x4 __attribute__((ext_vector_type(4)));

__device__ __forceinline__ float h2f(u16 u) { return __half2float(__ushort_as_half(u)); }
__device__ __forceinline__ u16   f2h(float f) { return __half_as_ushort(__float2half(f)); }
__device__ __forceinline__ u32   packh(float a, float b) {
    return (u32)f2h(a) | ((u32)f2h(b) << 16);
}
// zip slot for t-pair q (0..127): chunk-major, 9-u32 chunk stride (bank-clean)
__device__ __forceinline__ int zofs(int q) { return (q >> 3) * 9 + (q & 7); }

// ---------------- weight repack (all layers, one dispatch)
__global__ __launch_bounds__(256)
void wt_convert_all(const float* __restrict__ W0, const float* __restrict__ Wl,
                    u16* __restrict__ Wt0, u16* __restrict__ Wtl) {
    int id = blockIdx.x * 256 + threadIdx.x;
    const float* W; u16* outp; int NK, lg, chunk;
    if (id < 4096) { W = W0; outp = Wt0; NK = 4; lg = 2; chunk = id; }
    else {
        int r = id - 4096;
        int l = r >> 13;
        if (l >= 5) return;
        chunk = r & 8191;
        W = Wl + (size_t)l * H_DIM * H_DIM;
        outp = Wtl + (size_t)l * 65536;
        NK = 8; lg = 3;
    }
    int lane = chunk & 63;
    int rest = chunk >> 6;
    int n  = rest & 3; rest >>= 2;
    int kc = rest & (NK - 1);
    int w  = rest >> lg;
    int col = w * 64 + n + 4 * (lane & 15);
    int kb  = kc * 32 + (lane >> 4) * 8;
    u32 o[4];
    #pragma unroll
    for (int j = 0; j < 4; ++j)
        o[j] = packh(W[(size_t)(kb + 2 * j) * H_DIM + col],
                     W[(size_t)(kb + 2 * j + 1) * H_DIM + col]);
    *(uint4*)(outp + (size_t)chunk * 8) = uint4{o[0], o[1], o[2], o[3]};
}

// ---------------- MFMA GEMM, W-in-registers, fused bias + BN partial stats.
// psum layout is CHANNEL-MAJOR [256][NGB] so the scan prologue can reduce
// each channel with coalesced contiguous reads. No sync objects anywhere.
template<int K, bool AF32>
__global__ __launch_bounds__(256, 2)
void gemm_mfma(const void* Asrc, const u16* __restrict__ Wtc,
               const float* __restrict__ bias, u16* Yout, float2* __restrict__ psum) {
    constexpr int NK = K / 32;
    constexpr int AROWB = AF32 ? 272 : 528;
    __shared__ char Alds[64 * AROWB];
    const int tid  = threadIdx.x;
    const int lane = tid & 63;
    const int wave = tid >> 6;
    const int c    = lane & 15;
    const int g    = lane >> 4;
    const size_t brow = (size_t)blockIdx.x * 64;

    f16x8 wreg[NK][4];
    {
        const u16* base = Wtc + ((size_t)wave * NK * 4 * 64 + lane) * 8;
        #pragma unroll
        for (int kc = 0; kc < NK; ++kc)
            #pragma unroll
            for (int n = 0; n < 4; ++n)
                wreg[kc][n] = *(const f16x8*)(base + (size_t)(kc * 4 + n) * 64 * 8);
    }
    {
        const char* A = (const char*)Asrc + brow * 512;
        #pragma unroll
        for (int i = 0; i < 8; ++i) {
            int off = i * 4096 + tid * 16;
            int row = off >> 9, inb = off & 511;
            if (AF32) {
                float4 v = *(const float4*)(A + off);
                uint2 o = { packh(v.x, v.y), packh(v.z, v.w) };
                *(uint2*)(Alds + row * AROWB + (inb >> 1)) = o;
            } else {
                *(uint4*)(Alds + row * AROWB + inb) = *(const uint4*)(A + off);
            }
        }
    }
    __syncthreads();

    f32x4 acc[4][4];
    #pragma unroll
    for (int m = 0; m < 4; ++m)
        #pragma unroll
        for (int n = 0; n < 4; ++n)
            acc[m][n] = f32x4{0.f, 0.f, 0.f, 0.f};

    #pragma unroll
    for (int kc = 0; kc < NK; ++kc) {
        f16x8 afr[4];
        #pragma unroll
        for (int m = 0; m < 4; ++m) {
            int row = m * 16 + c;
            afr[m] = *(const f16x8*)(Alds + row * AROWB + kc * 64 + (g << 4));
        }
        #pragma unroll
        for (int m = 0; m < 4; ++m)
            #pragma unroll
            for (int n = 0; n < 4; ++n)
                acc[m][n] = __builtin_amdgcn_mfma_f32_16x16x32_f16(afr[m], wreg[kc][n], acc[m][n], 0, 0, 0);
    }

    float4 bv = *(const float4*)(bias + wave * 64 + 4 * c);
    float bb[4] = {bv.x, bv.y, bv.z, bv.w};
    float s[4] = {}, q[4] = {};
    #pragma unroll
    for (int m = 0; m < 4; ++m) {
        #pragma unroll
        for (int r = 0; r < 4; ++r) {
            float y0 = acc[m][0][r] + bb[0];
            float y1 = acc[m][1][r] + bb[1];
            float y2 = acc[m][2][r] + bb[2];
            float y3 = acc[m][3][r] + bb[3];
            s[0] += y0; q[0] = fmaf(y0, y0, q[0]);
            s[1] += y1; q[1] = fmaf(y1, y1, q[1]);
            s[2] += y2; q[2] = fmaf(y2, y2, q[2]);
            s[3] += y3; q[3] = fmaf(y3, y3, q[3]);
            size_t grow = brow + m * 16 + g * 4 + r;
            ushort4 o = { f2h(y0), f2h(y1), f2h(y2), f2h(y3) };
            *(ushort4*)(Yout + grow * H_DIM + wave * 64 + 4 * c) = o;
        }
    }
    #pragma unroll
    for (int n = 0; n < 4; ++n) {
        s[n] += __shfl_xor(s[n], 16, 64); s[n] += __shfl_xor(s[n], 32, 64);
        q[n] += __shfl_xor(q[n], 16, 64); q[n] += __shfl_xor(q[n], 32, 64);
    }
    if (g == 0) {
        #pragma unroll
        for (int n = 0; n < 4; ++n)
            psum[(size_t)(wave * 64 + 4 * c + n) * NGB + blockIdx.x] = float2{s[n], q[n]};
    }
}

// ---------------- scan32 + zero-sync BN finalize. Stream order guarantees
// psum[256][2048] is complete when the scan launches: each block reduces its
// own 32 channels from psum in the prologue (coalesced, L2/L3-hot), butterfly
// over the 16-lane chain group, A/SH in-register. No flags, no counters.
// Register-resident KS prefix + inter-tile carry (r18). LAST: skip apply+wb.
template<bool LAST>
__global__ __launch_bounds__(512, 8)
void scan32(u16* act, const float2* __restrict__ psum, const float* __restrict__ gamma,
            const float* __restrict__ beta, const float* __restrict__ uw) {
    __shared__ u32 Y32[XCB * XSTR];                           // 18560 B
    const int tid = threadIdx.x;
    const int cb  = ((int)blockIdx.x & 7) * 64 + ((int)blockIdx.x >> 3);  // XCD swizzle (512 blocks)
    u32* actG = (u32*)act;
    const int gcb = cb * 16;                                  // 16 u32 cols = 32 chains

    const int q  = tid >> 2;                                  // stage: t-pair 0..127
    const int pp = tid & 3;                                   // stage: 16B piece 0..3
    const int c  = tid >> 4;                                  // chain 0..31 (16-lane group)
    const int j  = tid & 15;                                  // chunk 0..15 (16 t each)
    const int cch = (cb * XCB + c) & (H_DIM - 1);

    // ---- prologue 1: issue tile-0 global loads first (fill the MEM pipe)
    uint4 ve, vo;
    {
        const size_t r0 = (size_t)(2 * q);
        ve = *(const uint4*)(actG + r0 * 8192 + gcb + pp * 4);
        vo = *(const uint4*)(actG + (r0 + 1) * 8192 + gcb + pp * 4);
    }

    // ---- prologue 2: BN finalize directly from psum (L2-hot; hides under loads)
    float A, SH;
    {
        float ss = 0.f, qq = 0.f;
        const float4* src = (const float4*)(psum + (size_t)cch * NGB + j * (NGB / 16));
        #pragma unroll 8
        for (int i = 0; i < NGB / 32; ++i) {                  // 64 float4 = 128 float2
            float4 p = src[i];
            ss += p.x + p.z;
            qq += p.y + p.w;
        }
        #pragma unroll
        for (int d = 1; d < 16; d <<= 1) {
            ss += __shfl_xor(ss, d, 16);
            qq += __shfl_xor(qq, d, 16);
        }
        const float inv = 1.0f / (float)M_DIM;
        float mm = ss * inv;
        float vv = qq * inv - mm * mm;
        A  = gamma[cch] * rsqrtf(vv + 1e-5f);
        SH = fmaf(-mm, A, beta[cch]);
    }
    const float U = uw[cch];

    float car = 0.f;                                          // inter-tile carry

    for (int tt = 0; tt < XNT; ++tt) {
        // ---- ds_write staged regs (tile tt), zip t-pairs per chain
        {
            const int ofs = zofs(q);
            u32 e[4] = {ve.x, ve.y, ve.z, ve.w};
            u32 o[4] = {vo.x, vo.y, vo.z, vo.w};
            #pragma unroll
            for (int m = 0; m < 4; ++m) {
                int ch = pp * 8 + 2 * m;
                Y32[ch * XSTR + ofs]       = (e[m] & 0xFFFFu) | (o[m] << 16);
                Y32[(ch + 1) * XSTR + ofs] = (e[m] >> 16)     | (o[m] & 0xFFFF0000u);
            }
        }
        __syncthreads();

        // ---- issue next tile's global loads (latency hides under compute)
        if (tt + 1 < XNT) {
            const size_t r0 = (size_t)(tt + 1) * XTT + 2 * q;
            ve = *(const uint4*)(actG + r0 * 8192 + gcb + pp * 4);
            vo = *(const uint4*)(actG + (r0 + 1) * 8192 + gcb + pp * 4);
        }

        // ---- compose my chunk (16 t = 8 u32) in registers
        u32 yw[8];
        #pragma unroll
        for (int k = 0; k < 8; ++k) yw[k] = Y32[c * XSTR + j * 9 + k];
        float a = 1.f, b = 0.f, cm = -1e30f;                  // identity; -1e30 avoids 0*inf
        #pragma unroll
        for (int k = 0; k < 8; ++k) {
            u32 w = yw[k];
            float yn0 = fmaf(A, h2f((u16)(w & 0xFFFF)), SH);
            a *= U; b = fmaf(U, b, yn0); cm = fmaxf(fmaf(U, cm, yn0), 0.f);
            float yn1 = fmaf(A, h2f((u16)(w >> 16)), SH);
            a *= U; b = fmaf(U, b, yn1); cm = fmaxf(fmaf(U, cm, yn1), 0.f);
        }

        // ---- KS width-16 compose-scan, all in-register (group = chain)
        #pragma unroll
        for (int d = 1; d < 16; d <<= 1) {
            float ai = __shfl_up(a, d, 16);
            float bi = __shfl_up(b, d, 16);
            float ci = __shfl_up(cm, d, 16);
            if (j >= d) {                                     // outer ∘ inner
                float nb = fmaf(a, bi, b);
                float nc = fmaxf(fmaf(a, ci, b), cm);
                a *= ai; b = nb; cm = nc;
            }
        }
        float ae = __shfl_up(a, 1, 16);
        float be = __shfl_up(b, 1, 16);
        float ce = __shfl_up(cm, 1, 16);
        float hin = (j == 0) ? car : fmaxf(fmaf(ae, car, be), ce);
        float a15 = __shfl(a, 15, 16);
        float b15 = __shfl(b, 15, 16);
        float c15 = __shfl(cm, 15, 16);
        car = fmaxf(fmaf(a15, car, b15), c15);                // carry for next tile

        if constexpr (!LAST) {
            // ---- apply from registers, pack h back into my Y32 slice
            float h = hin;
            #pragma unroll
            for (int k = 0; k < 8; ++k) {
                u32 w = yw[k];
                h = fmaxf(fmaf(U, h, fmaf(A, h2f((u16)(w & 0xFFFF)), SH)), 0.f);
                float hl = h;
                h = fmaxf(fmaf(U, h, fmaf(A, h2f((u16)(w >> 16)), SH)), 0.f);
                Y32[c * XSTR + j * 9 + k] = packh(hl, h);
            }
            __syncthreads();

            // ---- writeback (unzip): 64B contiguous per row per block
            {
                const size_t r0 = (size_t)tt * XTT + 2 * q;
                const int ofs = zofs(q);
                u32 e[4], o[4];
                #pragma unroll
                for (int m = 0; m < 4; ++m) {
                    int ch = pp * 8 + 2 * m;
                    u32 p0 = Y32[ch * XSTR + ofs];
                    u32 p1 = Y32[(ch + 1) * XSTR + ofs];
                    e[m] = (p0 & 0xFFFFu) | ((p1 & 0xFFFFu) << 16);
                    o[m] = (p0 >> 16)     | (p1 & 0xFFFF0000u);
                }
                *(uint4*)(actG + r0 * 8192 + gcb + pp * 4)       = uint4{e[0], e[1], e[2], e[3]};
                *(uint4*)(actG + (r0 + 1) * 8192 + gcb + pp * 4) = uint4{o[0], o[1], o[2], o[3]};
            }
            __syncthreads();   // Y32 free for next tile's ds_write
        } else {
            __syncthreads();   // compose reads done -> Y32 free for next ds_write
        }
    }

    if constexpr (LAST) {
        // car (uniform across the 16-lane group) IS h_{T-1} for chain c
        if (j == 15) {
            int chain = cb * XCB + c;
            act[(size_t)(T_DIM - 1) * S_DIM + chain] = f2h(car);
        }
    }
}

// ---------------- classifier: out[B,C] = h_last[B,H] @ Wc[H,C] + bc (f32 out)
__global__ __launch_bounds__(128)
void classifier(const u16* __restrict__ Hlast, const float* __restrict__ Wc,
                const float* __restrict__ bc, float* __restrict__ out) {
    __shared__ float hrow[H_DIM];
    const int b = blockIdx.x, tid = threadIdx.x;
    hrow[tid]       = h2f(Hlast[(size_t)b * H_DIM + tid]);
    hrow[tid + 128] = h2f(Hlast[(size_t)b * H_DIM + tid + 128]);
    __syncthreads();
    if (tid < C_DIM) {
        float s = bc[tid];
        #pragma unroll 8
        for (int hh = 0; hh < H_DIM; ++hh)
            s = fmaf(hrow[hh], Wc[(size_t)hh * C_DIM + tid], s);
        out[(size_t)b * C_DIM + tid] = s;
    }
}

extern "C" void kernel_launch(void* const* d_in, const int* in_sizes, int n_in,
                              void* d_out, int out_size, void* d_ws, size_t ws_size,
                              hipStream_t stream) {
    const float* x     = (const float*)d_in[0];
    const float* W0    = (const float*)d_in[1];
    const float* b0    = (const float*)d_in[2];
    const float* Wl    = (const float*)d_in[3];
    const float* bl    = (const float*)d_in[4];
    const float* u     = (const float*)d_in[5];
    const float* gamma = (const float*)d_in[6];
    const float* beta  = (const float*)d_in[7];
    const float* Wc    = (const float*)d_in[8];
    const float* bc    = (const float*)d_in[9];
    float* out = (float*)d_out;

    // workspace (~72 MB)
    char* ws = (char*)d_ws;
    u16* act = (u16*)ws;                 ws += (size_t)M_DIM * H_DIM * 2;   // 67.1 MB
    u16* Wt0 = (u16*)ws;                 ws += (size_t)32768 * 2;           // 64 KB
    u16* Wtl = (u16*)ws;                 ws += (size_t)5 * 65536 * 2;       // 640 KB
    float2* psum = (float2*)ws;          ws += (size_t)H_DIM * NGB * 8;     // 4 MB [256][2048]

    wt_convert_all<<<176, 256, 0, stream>>>(W0, Wl, Wt0, Wtl);

    for (int l = 0; l < L_DIM; ++l) {
        if (l == 0) {
            gemm_mfma<I_DIM, true><<<M_DIM / 64, 256, 0, stream>>>(x, Wt0, b0, act, psum);
        } else {
            gemm_mfma<H_DIM, false><<<M_DIM / 64, 256, 0, stream>>>(
                act, Wtl + (size_t)(l - 1) * 65536, bl + (size_t)(l - 1) * H_DIM, act, psum);
        }
        if (l < L_DIM - 1)
            scan32<false><<<S_DIM / XCB, 512, 0, stream>>>(act, psum, gamma + l * H_DIM,
                                                           beta + l * H_DIM, u + l * H_DIM);
        else
            scan32<true><<<S_DIM / XCB, 512, 0, stream>>>(act, psum, gamma + l * H_DIM,
                                                          beta + l * H_DIM, u + l * H_DIM);
    }
    classifier<<<B_DIM, 128, 0, stream>>>(act + (size_t)(T_DIM - 1) * S_DIM, Wc, bc, out);
}

// Round 23
// 388.932 us; speedup vs baseline: 1.3024x; 1.3024x over previous
//
#include <hip/hip_runtime.h>
#include <hip/hip_fp16.h>
#include <string.h>

#define T_DIM 2048
#define B_DIM 64
#define I_DIM 128
#define H_DIM 256
#define L_DIM 6
#define C_DIM 100
#define M_DIM (T_DIM * B_DIM)   // 131072 rows
#define S_DIM (B_DIM * H_DIM)   // 16384 chains
#define XCB 32                  // chains per scan block (64B row granule)
#define XSTR 145                // u32 stride per chain in LDS (16 chunks * 9 + pad)
#define XTT 256                 // timesteps per tile
#define XNT (T_DIM / XTT)       // 8 tiles

typedef unsigned short u16;
typedef unsigned int   u32;
typedef unsigned long long u64;
typedef _Float16 f16;
typedef f16   f16x8 __attribute__((ext_vector_type(8)));
typedef float f32x4 __attribute__((ext_vector_type(4)));

__device__ __forceinline__ float h2f(u16 u) { return __half2float(__ushort_as_half(u)); }
__device__ __forceinline__ u16   f2h(float f) { return __half_as_ushort(__float2half(f)); }
__device__ __forceinline__ u32   packh(float a, float b) {
    return (u32)f2h(a) | ((u32)f2h(b) << 16);
}
__device__ __forceinline__ u64 f2_to_u64(float2 v) { u64 r; memcpy(&r, &v, 8); return r; }
__device__ __forceinline__ float2 u64_to_f2(u64 v) { float2 r; memcpy(&r, &v, 8); return r; }
// zip slot for t-pair q (0..127): chunk-major, 9-u32 chunk stride (bank-clean)
__device__ __forceinline__ int zofs(int q) { return (q >> 3) * 9 + (q & 7); }

// ---------------- weight repack (all layers, one dispatch) + zero group counters
__global__ __launch_bounds__(256)
void wt_convert_all(const float* __restrict__ W0, const float* __restrict__ Wl,
                    u16* __restrict__ Wt0, u16* __restrict__ Wtl, u32* __restrict__ gcnt) {
    if (blockIdx.x == 0 && threadIdx.x < 64) gcnt[threadIdx.x] = 0;
    int id = blockIdx.x * 256 + threadIdx.x;
    const float* W; u16* outp; int NK, lg, chunk;
    if (id < 4096) { W = W0; outp = Wt0; NK = 4; lg = 2; chunk = id; }
    else {
        int r = id - 4096;
        int l = r >> 13;
        if (l >= 5) return;
        chunk = r & 8191;
        W = Wl + (size_t)l * H_DIM * H_DIM;
        outp = Wtl + (size_t)l * 65536;
        NK = 8; lg = 3;
    }
    int lane = chunk & 63;
    int rest = chunk >> 6;
    int n  = rest & 3; rest >>= 2;
    int kc = rest & (NK - 1);
    int w  = rest >> lg;
    int col = w * 64 + n + 4 * (lane & 15);
    int kb  = kc * 32 + (lane >> 4) * 8;
    u32 o[4];
    #pragma unroll
    for (int j = 0; j < 4; ++j)
        o[j] = packh(W[(size_t)(kb + 2 * j) * H_DIM + col],
                     W[(size_t)(kb + 2 * j + 1) * H_DIM + col]);
    *(uint4*)(outp + (size_t)chunk * 8) = uint4{o[0], o[1], o[2], o[3]};
}

// ---------------- MFMA GEMM (r21 body) + fenceless group-complete reduce tail.
// psum stores are agent-scope relaxed atomics (write-through; no threadfence).
// __syncthreads drains vmcnt; each block takes ONE relaxed ticket; the 32nd
// completer of its 32-block group (control-dependent, no spin) reduces the
// group's psum rows with agent-scope loads -> p2[64][256], re-arms counter.
template<int K, bool AF32>
__global__ __launch_bounds__(256, 2)
void gemm_mfma(const void* Asrc, const u16* __restrict__ Wtc,
               const float* __restrict__ bias, u16* Yout,
               float2* __restrict__ psum, float2* __restrict__ p2, u32* gcnt) {
    constexpr int NK = K / 32;
    constexpr int AROWB = AF32 ? 272 : 528;
    __shared__ char Alds[64 * AROWB];
    const int tid  = threadIdx.x;
    const int lane = tid & 63;
    const int wave = tid >> 6;
    const int c    = lane & 15;
    const int g    = lane >> 4;
    const size_t brow = (size_t)blockIdx.x * 64;

    f16x8 wreg[NK][4];
    {
        const u16* base = Wtc + ((size_t)wave * NK * 4 * 64 + lane) * 8;
        #pragma unroll
        for (int kc = 0; kc < NK; ++kc)
            #pragma unroll
            for (int n = 0; n < 4; ++n)
                wreg[kc][n] = *(const f16x8*)(base + (size_t)(kc * 4 + n) * 64 * 8);
    }
    {
        const char* A = (const char*)Asrc + brow * 512;
        #pragma unroll
        for (int i = 0; i < 8; ++i) {
            int off = i * 4096 + tid * 16;
            int row = off >> 9, inb = off & 511;
            if (AF32) {
                float4 v = *(const float4*)(A + off);
                uint2 o = { packh(v.x, v.y), packh(v.z, v.w) };
                *(uint2*)(Alds + row * AROWB + (inb >> 1)) = o;
            } else {
                *(uint4*)(Alds + row * AROWB + inb) = *(const uint4*)(A + off);
            }
        }
    }
    __syncthreads();

    f32x4 acc[4][4];
    #pragma unroll
    for (int m = 0; m < 4; ++m)
        #pragma unroll
        for (int n = 0; n < 4; ++n)
            acc[m][n] = f32x4{0.f, 0.f, 0.f, 0.f};

    #pragma unroll
    for (int kc = 0; kc < NK; ++kc) {
        f16x8 afr[4];
        #pragma unroll
        for (int m = 0; m < 4; ++m) {
            int row = m * 16 + c;
            afr[m] = *(const f16x8*)(Alds + row * AROWB + kc * 64 + (g << 4));
        }
        #pragma unroll
        for (int m = 0; m < 4; ++m)
            #pragma unroll
            for (int n = 0; n < 4; ++n)
                acc[m][n] = __builtin_amdgcn_mfma_f32_16x16x32_f16(afr[m], wreg[kc][n], acc[m][n], 0, 0, 0);
    }

    float4 bv = *(const float4*)(bias + wave * 64 + 4 * c);
    float bb[4] = {bv.x, bv.y, bv.z, bv.w};
    float s[4] = {}, q[4] = {};
    #pragma unroll
    for (int m = 0; m < 4; ++m) {
        #pragma unroll
        for (int r = 0; r < 4; ++r) {
            float y0 = acc[m][0][r] + bb[0];
            float y1 = acc[m][1][r] + bb[1];
            float y2 = acc[m][2][r] + bb[2];
            float y3 = acc[m][3][r] + bb[3];
            s[0] += y0; q[0] = fmaf(y0, y0, q[0]);
            s[1] += y1; q[1] = fmaf(y1, y1, q[1]);
            s[2] += y2; q[2] = fmaf(y2, y2, q[2]);
            s[3] += y3; q[3] = fmaf(y3, y3, q[3]);
            size_t grow = brow + m * 16 + g * 4 + r;
            ushort4 o = { f2h(y0), f2h(y1), f2h(y2), f2h(y3) };
            *(ushort4*)(Yout + grow * H_DIM + wave * 64 + 4 * c) = o;
        }
    }
    #pragma unroll
    for (int n = 0; n < 4; ++n) {
        s[n] += __shfl_xor(s[n], 16, 64); s[n] += __shfl_xor(s[n], 32, 64);
        q[n] += __shfl_xor(q[n], 16, 64); q[n] += __shfl_xor(q[n], 32, 64);
    }
    if (g == 0) {
        u64* dst = (u64*)(psum + (size_t)blockIdx.x * 256 + wave * 64 + 4 * c);
        #pragma unroll
        for (int n = 0; n < 4; ++n)
            __hip_atomic_store(dst + n, f2_to_u64(float2{s[n], q[n]}),
                               __ATOMIC_RELAXED, __HIP_MEMORY_SCOPE_AGENT);
    }
    __syncthreads();                         // drains vmcnt: psum stores at coherence point
    __shared__ u32 tk;
    if (tid == 0) tk = atomicAdd(&gcnt[blockIdx.x >> 5], 1);   // device-scope RMW
    __syncthreads();
    if (tk == 31) {                          // last of my group: all 32 rows visible
        const int g32 = blockIdx.x >> 5;
        float ss = 0.f, qq = 0.f;
        #pragma unroll 8
        for (int i = 0; i < 32; ++i) {
            u64 raw = __hip_atomic_load((const u64*)(psum + (size_t)(g32 * 32 + i) * 256 + tid),
                                        __ATOMIC_RELAXED, __HIP_MEMORY_SCOPE_AGENT);
            float2 p = u64_to_f2(raw);
            ss += p.x; qq += p.y;
        }
        p2[g32 * 256 + tid] = float2{ss, qq};   // kernel-end release covers the scan
        if (tid == 0) atomicExch(&gcnt[g32], 0);   // re-arm for next layer
    }
}

// ---------------- scan32 + BN finalize from p2 (r19-proven prologue).
// 32 chains/block (64B granule), register-resident KS prefix + carry (r18).
// Prologue: after issuing tile-0 loads, 16 lanes/chain reduce the 64 p2 rows
// (16 KB/block, L2-hot) + shfl_xor butterfly -> A/SH in-register.
// LAST: skip apply+writeback; carry after the loop IS h_{T-1}.
template<bool LAST>
__global__ __launch_bounds__(512, 8)
void scan32(u16* act, const float2* __restrict__ p2, const float* __restrict__ gamma,
            const float* __restrict__ beta, const float* __restrict__ uw) {
    __shared__ u32 Y32[XCB * XSTR];                           // 18560 B
    const int tid = threadIdx.x;
    const int cb  = ((int)blockIdx.x & 7) * 64 + ((int)blockIdx.x >> 3);  // XCD swizzle (512 blocks)
    u32* actG = (u32*)act;
    const int gcb = cb * 16;                                  // 16 u32 cols = 32 chains

    const int q  = tid >> 2;                                  // stage: t-pair 0..127
    const int pp = tid & 3;                                   // stage: 16B piece 0..3
    const int c  = tid >> 4;                                  // chain 0..31 (16-lane group)
    const int j  = tid & 15;                                  // chunk 0..15 (16 t each)
    const int cch = (cb * XCB + c) & (H_DIM - 1);

    // ---- prologue 1: issue tile-0 global loads first (fill the MEM pipe)
    uint4 ve, vo;
    {
        const size_t r0 = (size_t)(2 * q);
        ve = *(const uint4*)(actG + r0 * 8192 + gcb + pp * 4);
        vo = *(const uint4*)(actG + (r0 + 1) * 8192 + gcb + pp * 4);
    }

    // ---- prologue 2: BN finalize from p2 (hides under the loads above)
    float A, SH;
    {
        float ss = 0.f, qq = 0.f;
        #pragma unroll
        for (int r = 0; r < 4; ++r) {
            float2 p = p2[(size_t)(j * 4 + r) * 256 + cch];
            ss += p.x; qq += p.y;
        }
        #pragma unroll
        for (int d = 1; d < 16; d <<= 1) {
            ss += __shfl_xor(ss, d, 16);
            qq += __shfl_xor(qq, d, 16);
        }
        const float inv = 1.0f / (float)M_DIM;
        float mm = ss * inv;
        float vv = qq * inv - mm * mm;
        A  = gamma[cch] * rsqrtf(vv + 1e-5f);
        SH = fmaf(-mm, A, beta[cch]);
    }
    const float U = uw[cch];

    float car = 0.f;                                          // inter-tile carry

    for (int tt = 0; tt < XNT; ++tt) {
        // ---- ds_write staged regs (tile tt), zip t-pairs per chain
        {
            const int ofs = zofs(q);
            u32 e[4] = {ve.x, ve.y, ve.z, ve.w};
            u32 o[4] = {vo.x, vo.y, vo.z, vo.w};
            #pragma unroll
            for (int m = 0; m < 4; ++m) {
                int ch = pp * 8 + 2 * m;
                Y32[ch * XSTR + ofs]       = (e[m] & 0xFFFFu) | (o[m] << 16);
                Y32[(ch + 1) * XSTR + ofs] = (e[m] >> 16)     | (o[m] & 0xFFFF0000u);
            }
        }
        __syncthreads();

        // ---- issue next tile's global loads (latency hides under compute)
        if (tt + 1 < XNT) {
            const size_t r0 = (size_t)(tt + 1) * XTT + 2 * q;
            ve = *(const uint4*)(actG + r0 * 8192 + gcb + pp * 4);
            vo = *(const uint4*)(actG + (r0 + 1) * 8192 + gcb + pp * 4);
        }

        // ---- compose my chunk (16 t = 8 u32) in registers
        u32 yw[8];
        #pragma unroll
        for (int k = 0; k < 8; ++k) yw[k] = Y32[c * XSTR + j * 9 + k];
        float a = 1.f, b = 0.f, cm = -1e30f;                  // identity; -1e30 avoids 0*inf
        #pragma unroll
        for (int k = 0; k < 8; ++k) {
            u32 w = yw[k];
            float yn0 = fmaf(A, h2f((u16)(w & 0xFFFF)), SH);
            a *= U; b = fmaf(U, b, yn0); cm = fmaxf(fmaf(U, cm, yn0), 0.f);
            float yn1 = fmaf(A, h2f((u16)(w >> 16)), SH);
            a *= U; b = fmaf(U, b, yn1); cm = fmaxf(fmaf(U, cm, yn1), 0.f);
        }

        // ---- KS width-16 compose-scan, all in-register (group = chain)
        #pragma unroll
        for (int d = 1; d < 16; d <<= 1) {
            float ai = __shfl_up(a, d, 16);
            float bi = __shfl_up(b, d, 16);
            float ci = __shfl_up(cm, d, 16);
            if (j >= d) {                                     // outer ∘ inner
                float nb = fmaf(a, bi, b);
                float nc = fmaxf(fmaf(a, ci, b), cm);
                a *= ai; b = nb; cm = nc;
            }
        }
        float ae = __shfl_up(a, 1, 16);
        float be = __shfl_up(b, 1, 16);
        float ce = __shfl_up(cm, 1, 16);
        float hin = (j == 0) ? car : fmaxf(fmaf(ae, car, be), ce);
        float a15 = __shfl(a, 15, 16);
        float b15 = __shfl(b, 15, 16);
        float c15 = __shfl(cm, 15, 16);
        car = fmaxf(fmaf(a15, car, b15), c15);                // carry for next tile

        if constexpr (!LAST) {
            // ---- apply from registers, pack h back into my Y32 slice
            float h = hin;
            #pragma unroll
            for (int k = 0; k < 8; ++k) {
                u32 w = yw[k];
                h = fmaxf(fmaf(U, h, fmaf(A, h2f((u16)(w & 0xFFFF)), SH)), 0.f);
                float hl = h;
                h = fmaxf(fmaf(U, h, fmaf(A, h2f((u16)(w >> 16)), SH)), 0.f);
                Y32[c * XSTR + j * 9 + k] = packh(hl, h);
            }
            __syncthreads();

            // ---- writeback (unzip): 64B contiguous per row per block
            {
                const size_t r0 = (size_t)tt * XTT + 2 * q;
                const int ofs = zofs(q);
                u32 e[4], o[4];
                #pragma unroll
                for (int m = 0; m < 4; ++m) {
                    int ch = pp * 8 + 2 * m;
                    u32 p0 = Y32[ch * XSTR + ofs];
                    u32 p1 = Y32[(ch + 1) * XSTR + ofs];
                    e[m] = (p0 & 0xFFFFu) | ((p1 & 0xFFFFu) << 16);
                    o[m] = (p0 >> 16)     | (p1 & 0xFFFF0000u);
                }
                *(uint4*)(actG + r0 * 8192 + gcb + pp * 4)       = uint4{e[0], e[1], e[2], e[3]};
                *(uint4*)(actG + (r0 + 1) * 8192 + gcb + pp * 4) = uint4{o[0], o[1], o[2], o[3]};
            }
            __syncthreads();   // Y32 free for next tile's ds_write
        } else {
            __syncthreads();   // compose reads done -> Y32 free for next ds_write
        }
    }

    if constexpr (LAST) {
        // car (uniform across the 16-lane group) IS h_{T-1} for chain c
        if (j == 15) {
            int chain = cb * XCB + c;
            act[(size_t)(T_DIM - 1) * S_DIM + chain] = f2h(car);
        }
    }
}

// ---------------- classifier: out[B,C] = h_last[B,H] @ Wc[H,C] + bc (f32 out)
__global__ __launch_bounds__(128)
void classifier(const u16* __restrict__ Hlast, const float* __restrict__ Wc,
                const float* __restrict__ bc, float* __restrict__ out) {
    __shared__ float hrow[H_DIM];
    const int b = blockIdx.x, tid = threadIdx.x;
    hrow[tid]       = h2f(Hlast[(size_t)b * H_DIM + tid]);
    hrow[tid + 128] = h2f(Hlast[(size_t)b * H_DIM + tid + 128]);
    __syncthreads();
    if (tid < C_DIM) {
        float s = bc[tid];
        #pragma unroll 8
        for (int hh = 0; hh < H_DIM; ++hh)
            s = fmaf(hrow[hh], Wc[(size_t)hh * C_DIM + tid], s);
        out[(size_t)b * C_DIM + tid] = s;
    }
}

extern "C" void kernel_launch(void* const* d_in, const int* in_sizes, int n_in,
                              void* d_out, int out_size, void* d_ws, size_t ws_size,
                              hipStream_t stream) {
    const float* x     = (const float*)d_in[0];
    const float* W0    = (const float*)d_in[1];
    const float* b0    = (const float*)d_in[2];
    const float* Wl    = (const float*)d_in[3];
    const float* bl    = (const float*)d_in[4];
    const float* u     = (const float*)d_in[5];
    const float* gamma = (const float*)d_in[6];
    const float* beta  = (const float*)d_in[7];
    const float* Wc    = (const float*)d_in[8];
    const float* bc    = (const float*)d_in[9];
    float* out = (float*)d_out;

    // workspace (~72 MB)
    char* ws = (char*)d_ws;
    u16* act = (u16*)ws;                 ws += (size_t)M_DIM * H_DIM * 2;   // 67.1 MB
    u16* Wt0 = (u16*)ws;                 ws += (size_t)32768 * 2;           // 64 KB
    u16* Wtl = (u16*)ws;                 ws += (size_t)5 * 65536 * 2;       // 640 KB
    float2* psum = (float2*)ws;          ws += (size_t)2048 * 256 * 8;      // 4 MB [2048][256]
    float2* p2 = (float2*)ws;            ws += (size_t)64 * 256 * 8;        // 128 KB
    u32* gcnt  = (u32*)ws;               ws += 64 * 4;                      // 256 B

    wt_convert_all<<<176, 256, 0, stream>>>(W0, Wl, Wt0, Wtl, gcnt);

    for (int l = 0; l < L_DIM; ++l) {
        if (l == 0) {
            gemm_mfma<I_DIM, true><<<M_DIM / 64, 256, 0, stream>>>(x, Wt0, b0, act, psum, p2, gcnt);
        } else {
            gemm_mfma<H_DIM, false><<<M_DIM / 64, 256, 0, stream>>>(
                act, Wtl + (size_t)(l - 1) * 65536, bl + (size_t)(l - 1) * H_DIM,
                act, psum, p2, gcnt);
        }
        if (l < L_DIM - 1)
            scan32<false><<<S_DIM / XCB, 512, 0, stream>>>(act, p2, gamma + l * H_DIM,
                                                           beta + l * H_DIM, u + l * H_DIM);
        else
            scan32<true><<<S_DIM / XCB, 512, 0, stream>>>(act, p2, gamma + l * H_DIM,
                                                          beta + l * H_DIM, u + l * H_DIM);
    }
    classifier<<<B_DIM, 128, 0, stream>>>(act + (size_t)(T_DIM - 1) * S_DIM, Wc, bc, out);
}

// Round 24
// 358.468 us; speedup vs baseline: 1.4131x; 1.0850x over previous
//
#include <hip/hip_runtime.h>
#include <hip/hip_fp16.h>
#include <string.h>

#define T_DIM 2048
#define B_DIM 64
#define I_DIM 128
#define H_DIM 256
#define L_DIM 6
#define C_DIM 100
#define M_DIM (T_DIM * B_DIM)   // 131072 rows
#define S_DIM (B_DIM * H_DIM)   // 16384 chains
#define XCB 32                  // chains per scan/compose block (64B row granule)
#define XSTR 145                // u32 stride per chain in LDS (16 chunks * 9 + pad)
#define XTT 256                 // timesteps per tile
#define XNT (T_DIM / XTT)       // 8 tiles
#define NCK 32                  // h checkpoints per chain (every 64 t)

typedef unsigned short u16;
typedef unsigned int   u32;
typedef unsigned long long u64;
typedef _Float16 f16;
typedef f16   f16x8 __attribute__((ext_vector_type(8)));
typedef float f32x4 __attribute__((ext_vector_type(4)));

__device__ __forceinline__ float h2f(u16 u) { return __half2float(__ushort_as_half(u)); }
__device__ __forceinline__ u16   f2h(float f) { return __half_as_ushort(__float2half(f)); }
__device__ __forceinline__ u32   packh(float a, float b) {
    return (u32)f2h(a) | ((u32)f2h(b) << 16);
}
__device__ __forceinline__ u64 f2_to_u64(float2 v) { u64 r; memcpy(&r, &v, 8); return r; }
__device__ __forceinline__ float2 u64_to_f2(u64 v) { float2 r; memcpy(&r, &v, 8); return r; }
__device__ __forceinline__ int zofs(int q) { return (q >> 3) * 9 + (q & 7); }

// ---------------- weight repack (all layers, one dispatch) + zero group counters
__global__ __launch_bounds__(256)
void wt_convert_all(const float* __restrict__ W0, const float* __restrict__ Wl,
                    u16* __restrict__ Wt0, u16* __restrict__ Wtl, u32* __restrict__ gcnt) {
    if (blockIdx.x == 0 && threadIdx.x < 64) gcnt[threadIdx.x] = 0;
    int id = blockIdx.x * 256 + threadIdx.x;
    const float* W; u16* outp; int NK, lg, chunk;
    if (id < 4096) { W = W0; outp = Wt0; NK = 4; lg = 2; chunk = id; }
    else {
        int r = id - 4096;
        int l = r >> 13;
        if (l >= 5) return;
        chunk = r & 8191;
        W = Wl + (size_t)l * H_DIM * H_DIM;
        outp = Wtl + (size_t)l * 65536;
        NK = 8; lg = 3;
    }
    int lane = chunk & 63;
    int rest = chunk >> 6;
    int n  = rest & 3; rest >>= 2;
    int kc = rest & (NK - 1);
    int w  = rest >> lg;
    int col = w * 64 + n + 4 * (lane & 15);
    int kb  = kc * 32 + (lane >> 4) * 8;
    u32 o[4];
    #pragma unroll
    for (int j = 0; j < 4; ++j)
        o[j] = packh(W[(size_t)(kb + 2 * j) * H_DIM + col],
                     W[(size_t)(kb + 2 * j + 1) * H_DIM + col]);
    *(uint4*)(outp + (size_t)chunk * 8) = uint4{o[0], o[1], o[2], o[3]};
}

// ---------------- MFMA GEMM (r23 body + tail) with optional h-recompute.
// RECOMP=false (layer 0): contiguous 64-row tiles, A = x (f32).
// RECOMP=true (layers 1..5): b-fixed tiles (block = batch b, t in [tg*64,tg*64+64));
// after staging y (f16) the block recomputes h per channel from checkpoint
// hin[tg][chain] with BN params af/shf and recurrent u of the PREVIOUS layer,
// overwriting LDS, then runs the MFMA on h. Arithmetic identical to old apply.
template<int K, bool AF32, bool RECOMP>
__global__ __launch_bounds__(256, 2)
void gemm_mfma(const void* Asrc, const u16* __restrict__ Wtc,
               const float* __restrict__ bias, u16* Yout,
               float2* __restrict__ psum, float2* __restrict__ p2, u32* gcnt,
               const float* __restrict__ af, const float* __restrict__ shf,
               const float* __restrict__ uprev, const float* __restrict__ hin) {
    constexpr int NK = K / 32;
    constexpr int AROWB = AF32 ? 272 : 528;
    __shared__ char Alds[64 * AROWB];
    const int tid  = threadIdx.x;
    const int lane = tid & 63;
    const int wave = tid >> 6;
    const int c    = lane & 15;
    const int g    = lane >> 4;
    // tile row mapping
    const int bb = RECOMP ? ((int)blockIdx.x & 63) : 0;      // batch (RECOMP)
    const int tg = RECOMP ? ((int)blockIdx.x >> 6) : 0;      // 64-t group (RECOMP)
    const size_t brow = RECOMP ? 0 : (size_t)blockIdx.x * 64; // contiguous base (else)

    f16x8 wreg[NK][4];
    {
        const u16* base = Wtc + ((size_t)wave * NK * 4 * 64 + lane) * 8;
        #pragma unroll
        for (int kc = 0; kc < NK; ++kc)
            #pragma unroll
            for (int n = 0; n < 4; ++n)
                wreg[kc][n] = *(const f16x8*)(base + (size_t)(kc * 4 + n) * 64 * 8);
    }
    {
        const char* A = (const char*)Asrc;
        #pragma unroll
        for (int i = 0; i < 8; ++i) {
            int off = i * 4096 + tid * 16;
            int row = off >> 9, inb = off & 511;
            size_t gin = RECOMP ? (((size_t)(tg * 64 + row) * 64 + bb) * 512 + inb)
                                : ((brow + row) * 512 + inb);
            if (AF32) {
                float4 v = *(const float4*)(A + gin);
                uint2 o = { packh(v.x, v.y), packh(v.z, v.w) };
                *(uint2*)(Alds + row * AROWB + (inb >> 1)) = o;
            } else {
                *(uint4*)(Alds + row * AROWB + inb) = *(const uint4*)(A + gin);
            }
        }
    }
    __syncthreads();

    if constexpr (RECOMP) {
        // recompute h for my channel over the 64 staged timesteps (f32 chain,
        // f16 rounding on store — identical to the old apply semantics)
        const int ch = tid;                                   // 0..255
        const float A2 = af[ch], SH2 = shf[ch], U2 = uprev[ch];
        float h = hin[(size_t)tg * S_DIM + bb * 256 + ch];
        #pragma unroll
        for (int i = 0; i < 64; ++i) {
            u16* p = (u16*)(Alds + i * AROWB) + ch;
            float y = h2f(*p);
            h = fmaxf(fmaf(U2, h, fmaf(A2, y, SH2)), 0.f);
            *p = f2h(h);
        }
        __syncthreads();
    }

    f32x4 acc[4][4];
    #pragma unroll
    for (int m = 0; m < 4; ++m)
        #pragma unroll
        for (int n = 0; n < 4; ++n)
            acc[m][n] = f32x4{0.f, 0.f, 0.f, 0.f};

    #pragma unroll
    for (int kc = 0; kc < NK; ++kc) {
        f16x8 afr[4];
        #pragma unroll
        for (int m = 0; m < 4; ++m) {
            int row = m * 16 + c;
            afr[m] = *(const f16x8*)(Alds + row * AROWB + kc * 64 + (g << 4));
        }
        #pragma unroll
        for (int m = 0; m < 4; ++m)
            #pragma unroll
            for (int n = 0; n < 4; ++n)
                acc[m][n] = __builtin_amdgcn_mfma_f32_16x16x32_f16(afr[m], wreg[kc][n], acc[m][n], 0, 0, 0);
    }

    float4 bv = *(const float4*)(bias + wave * 64 + 4 * c);
    float bb4[4] = {bv.x, bv.y, bv.z, bv.w};
    float s[4] = {}, q[4] = {};
    #pragma unroll
    for (int m = 0; m < 4; ++m) {
        #pragma unroll
        for (int r = 0; r < 4; ++r) {
            float y0 = acc[m][0][r] + bb4[0];
            float y1 = acc[m][1][r] + bb4[1];
            float y2 = acc[m][2][r] + bb4[2];
            float y3 = acc[m][3][r] + bb4[3];
            s[0] += y0; q[0] = fmaf(y0, y0, q[0]);
            s[1] += y1; q[1] = fmaf(y1, y1, q[1]);
            s[2] += y2; q[2] = fmaf(y2, y2, q[2]);
            s[3] += y3; q[3] = fmaf(y3, y3, q[3]);
            int trow = m * 16 + g * 4 + r;                    // tile row
            size_t grow = RECOMP ? ((size_t)(tg * 64 + trow) * 64 + bb)
                                 : (brow + trow);
            ushort4 o = { f2h(y0), f2h(y1), f2h(y2), f2h(y3) };
            *(ushort4*)(Yout + grow * H_DIM + wave * 64 + 4 * c) = o;
        }
    }
    #pragma unroll
    for (int n = 0; n < 4; ++n) {
        s[n] += __shfl_xor(s[n], 16, 64); s[n] += __shfl_xor(s[n], 32, 64);
        q[n] += __shfl_xor(q[n], 16, 64); q[n] += __shfl_xor(q[n], 32, 64);
    }
    if (g == 0) {
        u64* dst = (u64*)(psum + (size_t)blockIdx.x * 256 + wave * 64 + 4 * c);
        #pragma unroll
        for (int n = 0; n < 4; ++n)
            __hip_atomic_store(dst + n, f2_to_u64(float2{s[n], q[n]}),
                               __ATOMIC_RELAXED, __HIP_MEMORY_SCOPE_AGENT);
    }
    __syncthreads();                         // drains vmcnt: psum at coherence point
    __shared__ u32 tk;
    if (tid == 0) tk = atomicAdd(&gcnt[blockIdx.x >> 5], 1);
    __syncthreads();
    if (tk == 31) {                          // last of my 32-block group
        const int g32 = blockIdx.x >> 5;
        float ss = 0.f, qq = 0.f;
        #pragma unroll 8
        for (int i = 0; i < 32; ++i) {
            u64 raw = __hip_atomic_load((const u64*)(psum + (size_t)(g32 * 32 + i) * 256 + tid),
                                        __ATOMIC_RELAXED, __HIP_MEMORY_SCOPE_AGENT);
            float2 p = u64_to_f2(raw);
            ss += p.x; qq += p.y;
        }
        p2[g32 * 256 + tid] = float2{ss, qq};
        if (tid == 0) atomicExch(&gcnt[g32], 0);
    }
}

// ---------------- compose: scan32 minus apply/writeback. Reads y (same staged
// 64B-granule pattern), BN finalize from p2 in prologue, composes + KS-16 +
// carry, and stores: h checkpoints every 64 t (j%4==0) and af/shf (blocks
// covering channels 0..255 once). Writes 2 MB instead of 67 MB.
__global__ __launch_bounds__(512, 8)
void compose32(const u16* __restrict__ act, const float2* __restrict__ p2,
               const float* __restrict__ gamma, const float* __restrict__ beta,
               const float* __restrict__ uw, float* __restrict__ hin,
               float* __restrict__ af, float* __restrict__ shf) {
    __shared__ u32 Y32[XCB * XSTR];
    const int tid = threadIdx.x;
    const int cb  = ((int)blockIdx.x & 7) * 64 + ((int)blockIdx.x >> 3);  // XCD swizzle
    const u32* actG = (const u32*)act;
    const int gcb = cb * 16;

    const int q  = tid >> 2;
    const int pp = tid & 3;
    const int c  = tid >> 4;
    const int j  = tid & 15;
    const int cch = (cb * XCB + c) & (H_DIM - 1);
    const int chain = cb * XCB + c;

    uint4 ve, vo;
    {
        const size_t r0 = (size_t)(2 * q);
        ve = *(const uint4*)(actG + r0 * 8192 + gcb + pp * 4);
        vo = *(const uint4*)(actG + (r0 + 1) * 8192 + gcb + pp * 4);
    }

    float A, SH;
    {
        float ss = 0.f, qq = 0.f;
        #pragma unroll
        for (int r = 0; r < 4; ++r) {
            float2 p = p2[(size_t)(j * 4 + r) * 256 + cch];
            ss += p.x; qq += p.y;
        }
        #pragma unroll
        for (int d = 1; d < 16; d <<= 1) {
            ss += __shfl_xor(ss, d, 16);
            qq += __shfl_xor(qq, d, 16);
        }
        const float inv = 1.0f / (float)M_DIM;
        float mm = ss * inv;
        float vv = qq * inv - mm * mm;
        A  = gamma[cch] * rsqrtf(vv + 1e-5f);
        SH = fmaf(-mm, A, beta[cch]);
    }
    if (cb < 8 && j == 0) { af[cch] = A; shf[cch] = SH; }     // channels 0..255 once
    const float U = uw[cch];

    float car = 0.f;

    for (int tt = 0; tt < XNT; ++tt) {
        {
            const int ofs = zofs(q);
            u32 e[4] = {ve.x, ve.y, ve.z, ve.w};
            u32 o[4] = {vo.x, vo.y, vo.z, vo.w};
            #pragma unroll
            for (int m = 0; m < 4; ++m) {
                int ch = pp * 8 + 2 * m;
                Y32[ch * XSTR + ofs]       = (e[m] & 0xFFFFu) | (o[m] << 16);
                Y32[(ch + 1) * XSTR + ofs] = (e[m] >> 16)     | (o[m] & 0xFFFF0000u);
            }
        }
        __syncthreads();

        if (tt + 1 < XNT) {
            const size_t r0 = (size_t)(tt + 1) * XTT + 2 * q;
            ve = *(const uint4*)(actG + r0 * 8192 + gcb + pp * 4);
            vo = *(const uint4*)(actG + (r0 + 1) * 8192 + gcb + pp * 4);
        }

        u32 yw[8];
        #pragma unroll
        for (int k = 0; k < 8; ++k) yw[k] = Y32[c * XSTR + j * 9 + k];
        float a = 1.f, b = 0.f, cm = -1e30f;
        #pragma unroll
        for (int k = 0; k < 8; ++k) {
            u32 w = yw[k];
            float yn0 = fmaf(A, h2f((u16)(w & 0xFFFF)), SH);
            a *= U; b = fmaf(U, b, yn0); cm = fmaxf(fmaf(U, cm, yn0), 0.f);
            float yn1 = fmaf(A, h2f((u16)(w >> 16)), SH);
            a *= U; b = fmaf(U, b, yn1); cm = fmaxf(fmaf(U, cm, yn1), 0.f);
        }

        #pragma unroll
        for (int d = 1; d < 16; d <<= 1) {
            float ai = __shfl_up(a, d, 16);
            float bi = __shfl_up(b, d, 16);
            float ci = __shfl_up(cm, d, 16);
            if (j >= d) {
                float nb = fmaf(a, bi, b);
                float nc = fmaxf(fmaf(a, ci, b), cm);
                a *= ai; b = nb; cm = nc;
            }
        }
        float ae = __shfl_up(a, 1, 16);
        float be = __shfl_up(b, 1, 16);
        float ce = __shfl_up(cm, 1, 16);
        float hcp = (j == 0) ? car : fmaxf(fmaf(ae, car, be), ce);  // h at t = tt*256 + j*16
        float a15 = __shfl(a, 15, 16);
        float b15 = __shfl(b, 15, 16);
        float c15 = __shfl(cm, 15, 16);
        car = fmaxf(fmaf(a15, car, b15), c15);

        if ((j & 3) == 0)                                      // checkpoint every 64 t
            hin[(size_t)(tt * 4 + (j >> 2)) * S_DIM + chain] = hcp;

        __syncthreads();                                       // Y32 free for next tile
    }
}

// ---------------- scan_last (r23 scan32<true>): full scan, writes only h_{T-1}.
__global__ __launch_bounds__(512, 8)
void scan_last(u16* act, const float2* __restrict__ p2, const float* __restrict__ gamma,
               const float* __restrict__ beta, const float* __restrict__ uw) {
    __shared__ u32 Y32[XCB * XSTR];
    const int tid = threadIdx.x;
    const int cb  = ((int)blockIdx.x & 7) * 64 + ((int)blockIdx.x >> 3);
    u32* actG = (u32*)act;
    const int gcb = cb * 16;

    const int q  = tid >> 2;
    const int pp = tid & 3;
    const int c  = tid >> 4;
    const int j  = tid & 15;
    const int cch = (cb * XCB + c) & (H_DIM - 1);

    uint4 ve, vo;
    {
        const size_t r0 = (size_t)(2 * q);
        ve = *(const uint4*)(actG + r0 * 8192 + gcb + pp * 4);
        vo = *(const uint4*)(actG + (r0 + 1) * 8192 + gcb + pp * 4);
    }
    float A, SH;
    {
        float ss = 0.f, qq = 0.f;
        #pragma unroll
        for (int r = 0; r < 4; ++r) {
            float2 p = p2[(size_t)(j * 4 + r) * 256 + cch];
            ss += p.x; qq += p.y;
        }
        #pragma unroll
        for (int d = 1; d < 16; d <<= 1) {
            ss += __shfl_xor(ss, d, 16);
            qq += __shfl_xor(qq, d, 16);
        }
        const float inv = 1.0f / (float)M_DIM;
        float mm = ss * inv;
        float vv = qq * inv - mm * mm;
        A  = gamma[cch] * rsqrtf(vv + 1e-5f);
        SH = fmaf(-mm, A, beta[cch]);
    }
    const float U = uw[cch];
    float car = 0.f;

    for (int tt = 0; tt < XNT; ++tt) {
        {
            const int ofs = zofs(q);
            u32 e[4] = {ve.x, ve.y, ve.z, ve.w};
            u32 o[4] = {vo.x, vo.y, vo.z, vo.w};
            #pragma unroll
            for (int m = 0; m < 4; ++m) {
                int ch = pp * 8 + 2 * m;
                Y32[ch * XSTR + ofs]       = (e[m] & 0xFFFFu) | (o[m] << 16);
                Y32[(ch + 1) * XSTR + ofs] = (e[m] >> 16)     | (o[m] & 0xFFFF0000u);
            }
        }
        __syncthreads();
        if (tt + 1 < XNT) {
            const size_t r0 = (size_t)(tt + 1) * XTT + 2 * q;
            ve = *(const uint4*)(actG + r0 * 8192 + gcb + pp * 4);
            vo = *(const uint4*)(actG + (r0 + 1) * 8192 + gcb + pp * 4);
        }
        u32 yw[8];
        #pragma unroll
        for (int k = 0; k < 8; ++k) yw[k] = Y32[c * XSTR + j * 9 + k];
        float a = 1.f, b = 0.f, cm = -1e30f;
        #pragma unroll
        for (int k = 0; k < 8; ++k) {
            u32 w = yw[k];
            float yn0 = fmaf(A, h2f((u16)(w & 0xFFFF)), SH);
            a *= U; b = fmaf(U, b, yn0); cm = fmaxf(fmaf(U, cm, yn0), 0.f);
            float yn1 = fmaf(A, h2f((u16)(w >> 16)), SH);
            a *= U; b = fmaf(U, b, yn1); cm = fmaxf(fmaf(U, cm, yn1), 0.f);
        }
        #pragma unroll
        for (int d = 1; d < 16; d <<= 1) {
            float ai = __shfl_up(a, d, 16);
            float bi = __shfl_up(b, d, 16);
            float ci = __shfl_up(cm, d, 16);
            if (j >= d) {
                float nb = fmaf(a, bi, b);
                float nc = fmaxf(fmaf(a, ci, b), cm);
                a *= ai; b = nb; cm = nc;
            }
        }
        float a15 = __shfl(a, 15, 16);
        float b15 = __shfl(b, 15, 16);
        float c15 = __shfl(cm, 15, 16);
        car = fmaxf(fmaf(a15, car, b15), c15);
        __syncthreads();
    }
    if (j == 15) {
        int chain = cb * XCB + c;
        act[(size_t)(T_DIM - 1) * S_DIM + chain] = f2h(car);
    }
}

// ---------------- classifier: out[B,C] = h_last[B,H] @ Wc[H,C] + bc (f32 out)
__global__ __launch_bounds__(128)
void classifier(const u16* __restrict__ Hlast, const float* __restrict__ Wc,
                const float* __restrict__ bc, float* __restrict__ out) {
    __shared__ float hrow[H_DIM];
    const int b = blockIdx.x, tid = threadIdx.x;
    hrow[tid]       = h2f(Hlast[(size_t)b * H_DIM + tid]);
    hrow[tid + 128] = h2f(Hlast[(size_t)b * H_DIM + tid + 128]);
    __syncthreads();
    if (tid < C_DIM) {
        float s = bc[tid];
        #pragma unroll 8
        for (int hh = 0; hh < H_DIM; ++hh)
            s = fmaf(hrow[hh], Wc[(size_t)hh * C_DIM + tid], s);
        out[(size_t)b * C_DIM + tid] = s;
    }
}

extern "C" void kernel_launch(void* const* d_in, const int* in_sizes, int n_in,
                              void* d_out, int out_size, void* d_ws, size_t ws_size,
                              hipStream_t stream) {
    const float* x     = (const float*)d_in[0];
    const float* W0    = (const float*)d_in[1];
    const float* b0    = (const float*)d_in[2];
    const float* Wl    = (const float*)d_in[3];
    const float* bl    = (const float*)d_in[4];
    const float* u     = (const float*)d_in[5];
    const float* gamma = (const float*)d_in[6];
    const float* beta  = (const float*)d_in[7];
    const float* Wc    = (const float*)d_in[8];
    const float* bc    = (const float*)d_in[9];
    float* out = (float*)d_out;

    // workspace (~75 MB)
    char* ws = (char*)d_ws;
    u16* act = (u16*)ws;                 ws += (size_t)M_DIM * H_DIM * 2;   // 67.1 MB
    u16* Wt0 = (u16*)ws;                 ws += (size_t)32768 * 2;           // 64 KB
    u16* Wtl = (u16*)ws;                 ws += (size_t)5 * 65536 * 2;       // 640 KB
    float2* psum = (float2*)ws;          ws += (size_t)2048 * 256 * 8;      // 4 MB
    float2* p2 = (float2*)ws;            ws += (size_t)64 * 256 * 8;        // 128 KB
    float* hin = (float*)ws;             ws += (size_t)NCK * S_DIM * 4;     // 2 MB
    float* af  = (float*)ws;             ws += H_DIM * 4;
    float* shf = (float*)ws;             ws += H_DIM * 4;
    u32* gcnt  = (u32*)ws;               ws += 64 * 4;

    wt_convert_all<<<176, 256, 0, stream>>>(W0, Wl, Wt0, Wtl, gcnt);

    // layer 0: x -> y0 (contiguous tiles, no recompute)
    gemm_mfma<I_DIM, true, false><<<M_DIM / 64, 256, 0, stream>>>(
        x, Wt0, b0, act, psum, p2, gcnt, nullptr, nullptr, nullptr, nullptr);

    // layers 1..5: compose_{m-1} (checkpoints + af/shf) then gemm_m (recompute h inline)
    for (int m = 1; m < L_DIM; ++m) {
        compose32<<<S_DIM / XCB, 512, 0, stream>>>(act, p2, gamma + (m - 1) * H_DIM,
                                                   beta + (m - 1) * H_DIM,
                                                   u + (m - 1) * H_DIM, hin, af, shf);
        gemm_mfma<H_DIM, false, true><<<M_DIM / 64, 256, 0, stream>>>(
            act, Wtl + (size_t)(m - 1) * 65536, bl + (size_t)(m - 1) * H_DIM,
            act, psum, p2, gcnt, af, shf, u + (m - 1) * H_DIM, hin);
    }

    // layer 5 recurrence: only h_{T-1} needed
    scan_last<<<S_DIM / XCB, 512, 0, stream>>>(act, p2, gamma + 5 * H_DIM,
                                               beta + 5 * H_DIM, u + 5 * H_DIM);
    classifier<<<B_DIM, 128, 0, stream>>>(act + (size_t)(T_DIM - 1) * S_DIM, Wc, bc, out);
}